// Round 6
// baseline (626.620 us; speedup 1.0000x reference)
//
#include <hip/hip_runtime.h>

// SSIM 3D, round 9. Separable rank-1 window (u ⊗ v ⊗ t), fused W->H->D.
// r8 (barrier-free wave-private LDS) verified: main 66.6 µs, no spills.
// Remaining limiter: occupancy 33% (grid-capped: 1024 blk x 4 waves = 16
// waves/CU; VGPR/LDS allow 32). This round: WORK-CONSERVING occupancy double.
//   Wave stripe 32 cols -> 16 cols: per lane W-conv 4->2 cols (float2 loads),
//   H/D 2->1 col (scalar D-ring, -25 VGPR). Same total FLOPs. Wave-privacy
//   preserved (wave owns all 8 W-rows of its 16 cols) -> still ZERO barriers
//   in the main loop. Blocks stay 256 thr (4 waves = 64 block cols); grid
//   2048 = 8 blocks/CU exact = 32 waves/CU. LDS 10.25 KB/block (82 KB/CU ok).
// Known-good codegen shape preserved verbatim: 4x5-phase loop, asm memory
// fences at the two former barrier sites (spill guard: r4-r6 showed big
// unrolled regions without fences stack load live-ranges -> 0.5-1 GB scratch;
// watch WRITE_SIZE ~17 MB; VGPR_Count lies about spills).
// Tile per block: W=64 (4 waves x 16 cols), TH=4 rows, DSUB=16 -> 2048 blocks.

#define NDIM 128
#define TH 4
#define WR (TH + 4)            // 8 W-conv rows
#define DSUB 16
#define SW 64                  // block col-stripe width
#define NSS (NDIM / SW)        // 2
#define NHT (NDIM / TH)        // 32
#define NDT (NDIM / DSUB)      // 8
#define NB 4
#define NBLK (NHT * NDT * NB * NSS)  // 2048

__global__ void factorize_window(const float* __restrict__ w, float* __restrict__ ws) {
    if (threadIdx.x == 0) {
        float w000 = w[0];
        #pragma unroll
        for (int i = 0; i < 5; ++i) ws[i]      = w[i * 25];
        #pragma unroll
        for (int j = 0; j < 5; ++j) ws[5 + j]  = w[j * 5] / w000;
        #pragma unroll
        for (int k = 0; k < 5; ++k) ws[10 + k] = w[k] / w000;
    }
}

__launch_bounds__(256, 8)
__global__ void ssim_main(const float* __restrict__ img1,
                          const float* __restrict__ img2,
                          const float* __restrict__ wfac,
                          float* __restrict__ partials) {
    const int bid = blockIdx.x;
    const int ss  = bid & (NSS - 1);     // W half: 0 or 1
    const int idx = bid >> 1;
    const int th  = idx & (NHT - 1);
    const int td  = (idx >> 5) & (NDT - 1);
    const int b   = idx >> 8;

    const int h0 = th * TH, d0 = td * DSUB, cs = ss * SW;
    const float* __restrict__ x1 = img1 + (size_t)(b * 2 + 1) * NDIM * NDIM * NDIM;
    const float* __restrict__ x2 = img2 + (size_t)b * NDIM * NDIM * NDIM;

    float uW[5], vW[5], tW[5];
    #pragma unroll
    for (int i = 0; i < 5; ++i) { uW[i] = wfac[i]; vW[i] = wfac[5 + i]; tW[i] = wfac[10 + i]; }

    __shared__ float sWc[5][WR][SW];     // 10240 B; wave w owns cols [16w,16w+16)
    __shared__ float sRed[4];

    const int tid  = threadIdx.x;
    const int wvid = tid >> 6;           // wave id 0..3 -> 16-col stripe
    const int lane = tid & 63;
    // W-conv mapping (per wave): 8 rows x 8 col-groups of 2
    const int wrow = lane >> 3;          // 0..7
    const int wg   = lane & 7;           // 0..7
    const int c0b  = wvid * 16 + wg * 2; // block-local col of 2 outputs
    const int c0g  = cs + c0b;           // global col (even, 0..126)
    const int ghw  = h0 + wrow - 2;
    // H/D mapping (per wave): 4 rows x 16 single cols
    const int orow = lane >> 4;          // 0..3
    const int ocb  = wvid * 16 + (lane & 15);

    float ring[5][5];                    // [slot][field], static indices only
    float accS = 0.f;

#define PHASE(I, P) do {                                                       \
    const int i_ = (I);                                                        \
    const int d_ = d0 - 2 + i_;                                                \
    float2 A0 = make_float2(0.f, 0.f), A1 = A0, A2 = A0;                       \
    float2 B0 = A0, B1 = A0, B2 = A0;                                          \
    if (((unsigned)d_ < NDIM) && ((unsigned)ghw < NDIM)) {                     \
        const float* __restrict__ r1_ = x1 + ((size_t)d_ * NDIM + ghw) * NDIM; \
        const float* __restrict__ r2_ = x2 + ((size_t)d_ * NDIM + ghw) * NDIM; \
        if (c0g > 0)   { A0 = *(const float2*)(r1_ + c0g - 2);                 \
                         B0 = *(const float2*)(r2_ + c0g - 2); }               \
        A1 = *(const float2*)(r1_ + c0g);                                      \
        B1 = *(const float2*)(r2_ + c0g);                                      \
        if (c0g < 126) { A2 = *(const float2*)(r1_ + c0g + 2);                 \
                         B2 = *(const float2*)(r2_ + c0g + 2); }               \
    }                                                                          \
    float ra[6] = {A0.x,A0.y, A1.x,A1.y, A2.x,A2.y};                           \
    float rb[6] = {B0.x,B0.y, B1.x,B1.y, B2.x,B2.y};                           \
    float m1v[2], m2v[2], q11v[2], q22v[2], q12v[2];                           \
    _Pragma("unroll")                                                          \
    for (int k_ = 0; k_ < 2; ++k_) {                                           \
        float m1_=0.f, m2_=0.f, q11_=0.f, q22_=0.f, q12_=0.f;                  \
        _Pragma("unroll")                                                      \
        for (int c_ = 0; c_ < 5; ++c_) {                                       \
            const float a_ = ra[k_ + c_], b_ = rb[k_ + c_];                    \
            const float ta_ = tW[c_] * a_, tb_ = tW[c_] * b_;                  \
            m1_ += ta_; m2_ += tb_;                                            \
            q11_ += ta_ * a_; q22_ += tb_ * b_; q12_ += ta_ * b_;              \
        }                                                                      \
        m1v[k_]=m1_; m2v[k_]=m2_; q11v[k_]=q11_; q22v[k_]=q22_; q12v[k_]=q12_; \
    }                                                                          \
    /* fence: prior phase's intra-wave LDS reads ordered before these writes;  \
       HW processes a wave's DS ops in issue order. Also the scheduling fence  \
       that prevents cross-phase load-hoist spills (r4-r6). */                 \
    asm volatile("" ::: "memory");                                             \
    *(float2*)&sWc[0][wrow][c0b] = make_float2(m1v[0], m1v[1]);                \
    *(float2*)&sWc[1][wrow][c0b] = make_float2(m2v[0], m2v[1]);                \
    *(float2*)&sWc[2][wrow][c0b] = make_float2(q11v[0], q11v[1]);              \
    *(float2*)&sWc[3][wrow][c0b] = make_float2(q22v[0], q22v[1]);              \
    *(float2*)&sWc[4][wrow][c0b] = make_float2(q12v[0], q12v[1]);              \
    asm volatile("" ::: "memory");  /* writes ordered before the reads below */\
    _Pragma("unroll")                                                          \
    for (int f_ = 0; f_ < 5; ++f_) {                                           \
        float F_ = 0.f;                                                        \
        _Pragma("unroll")                                                      \
        for (int r_ = 0; r_ < 5; ++r_)                                         \
            F_ += vW[r_] * sWc[f_][orow + r_][ocb];                            \
        ring[(P)][f_] = F_;                                                    \
    }                                                                          \
    if (i_ >= 4) {                                                             \
        float F0 = 0.f, F1 = 0.f, F2 = 0.f, F3 = 0.f, F4 = 0.f;                \
        _Pragma("unroll")                                                      \
        for (int j_ = 0; j_ < 5; ++j_) {                                       \
            const int s_ = ((P) + 1 + j_) % 5;                                 \
            const float uw_ = uW[j_];                                          \
            F0 += uw_*ring[s_][0]; F1 += uw_*ring[s_][1];                      \
            F2 += uw_*ring[s_][2]; F3 += uw_*ring[s_][3];                      \
            F4 += uw_*ring[s_][4];                                             \
        }                                                                      \
        const float mu1 = F0, mu2 = F1;                                        \
        const float m11 = mu1*mu1, m22 = mu2*mu2, m12 = mu1*mu2;               \
        const float num = (2.f*m12 + 1e-4f) * (2.f*(F4 - m12) + 9e-4f);        \
        const float den = (m11 + m22 + 1e-4f) *                                \
                          ((F2 - m11) + (F3 - m22) + 9e-4f);                   \
        accS += __fdividef(num, den);                                          \
    }                                                                          \
} while (0)

    // 20 slices: d0-2 .. d0+17, 4 groups of 5 phases (known-good loop shape)
    for (int io = 0; io < 4; ++io) {
        const int ib = io * 5;
        PHASE(ib + 0, 0);
        PHASE(ib + 1, 1);
        PHASE(ib + 2, 2);
        PHASE(ib + 3, 3);
        PHASE(ib + 4, 4);
    }
#undef PHASE

    float acc = accS;
    #pragma unroll
    for (int off = 32; off > 0; off >>= 1)
        acc += __shfl_down(acc, off, 64);
    __syncthreads();                     // only cross-wave sync in the kernel
    if (lane == 0) sRed[wvid] = acc;
    __syncthreads();
    if (tid == 0) partials[bid] = sRed[0] + sRed[1] + sRed[2] + sRed[3];
}

__global__ void finalize_kernel(const float* __restrict__ partials, float* __restrict__ out) {
    const int tid = threadIdx.x;
    double s = 0.0;
    for (int i = tid; i < NBLK; i += 256) s += (double)partials[i];
    #pragma unroll
    for (int off = 32; off > 0; off >>= 1)
        s += __shfl_down(s, off, 64);
    __shared__ double sm[4];
    if ((tid & 63) == 0) sm[tid >> 6] = s;
    __syncthreads();
    if (tid == 0)
        out[0] = 1.0f - (float)((sm[0] + sm[1] + sm[2] + sm[3]) / (double)(4LL * 128 * 128 * 128));
}

extern "C" void kernel_launch(void* const* d_in, const int* in_sizes, int n_in,
                              void* d_out, int out_size, void* d_ws, size_t ws_size,
                              hipStream_t stream) {
    const float* img1 = (const float*)d_in[0];   // (4,2,128,128,128) fp32
    const float* img2 = (const float*)d_in[1];   // (4,1,128,128,128) fp32
    const float* win  = (const float*)d_in[2];   // (1,1,5,5,5) fp32
    float* out = (float*)d_out;
    float* ws  = (float*)d_ws;
    float* wfac     = ws;         // 16 floats
    float* partials = ws + 16;    // NBLK floats, fully rewritten every launch

    hipLaunchKernelGGL(factorize_window, dim3(1), dim3(64), 0, stream, win, wfac);
    hipLaunchKernelGGL(ssim_main, dim3(NBLK), dim3(256), 0, stream, img1, img2, wfac, partials);
    hipLaunchKernelGGL(finalize_kernel, dim3(1), dim3(256), 0, stream, partials, out);
}

// Round 7
// 278.435 us; speedup vs baseline: 2.2505x; 2.2505x over previous
//
#include <hip/hip_runtime.h>

// SSIM 3D, round 10 = round 9 with ONE line fixed: __launch_bounds__ back to
// (256,4). r9 post-mortem: promising 8 waves/EU squeezed the allocator to a
// 32-VGPR budget (VGPR_Count 64->32) for a ~50-float working set -> 1.1 GB
// scratch spills, 545 µs. The (256,4) bound is the battle-tested value in
// every non-spilling kernel this session; occupancy comes from resources:
// expected ~40-56 VGPR (r8's LARGER set fit 64) -> 8 waves/SIMD eligible,
// LDS 10.75 KB -> grid-capped 8 blocks/CU = 32 waves/CU (2x r8's TLP).
// Structure identical to r9 (= r8's verified barrier-free shape, narrowed):
//  - Wave-private LDS: wave owns all 8 W-rows x 16-col stripe; producer ==
//    consumer wave -> ZERO barriers in main loop; asm memory fences at the two
//    former barrier sites (spill/sched guard, r4-r6 lesson).
//  - Work-conserving split: per lane W-conv 2 cols (float2), H/D 1 col
//    (scalar ring); same total FLOPs as r8, double the blocks.
// Tripwires: WRITE_SIZE ~17-20 MB (spill detector; VGPR_Count lies),
// bank conflicts <5% of LDS ops.
// Tile per block: W=64 (4 waves x 16 cols), TH=4 rows, DSUB=16 -> 2048 blocks.

#define NDIM 128
#define TH 4
#define WR (TH + 4)            // 8 W-conv rows
#define DSUB 16
#define SW 64                  // block col-stripe width
#define NSS (NDIM / SW)        // 2
#define NHT (NDIM / TH)        // 32
#define NDT (NDIM / DSUB)      // 8
#define NB 4
#define NBLK (NHT * NDT * NB * NSS)  // 2048

__global__ void factorize_window(const float* __restrict__ w, float* __restrict__ ws) {
    if (threadIdx.x == 0) {
        float w000 = w[0];
        #pragma unroll
        for (int i = 0; i < 5; ++i) ws[i]      = w[i * 25];
        #pragma unroll
        for (int j = 0; j < 5; ++j) ws[5 + j]  = w[j * 5] / w000;
        #pragma unroll
        for (int k = 0; k < 5; ++k) ws[10 + k] = w[k] / w000;
    }
}

__launch_bounds__(256, 4)
__global__ void ssim_main(const float* __restrict__ img1,
                          const float* __restrict__ img2,
                          const float* __restrict__ wfac,
                          float* __restrict__ partials) {
    const int bid = blockIdx.x;
    const int ss  = bid & (NSS - 1);     // W half: 0 or 1
    const int idx = bid >> 1;
    const int th  = idx & (NHT - 1);
    const int td  = (idx >> 5) & (NDT - 1);
    const int b   = idx >> 8;

    const int h0 = th * TH, d0 = td * DSUB, cs = ss * SW;
    const float* __restrict__ x1 = img1 + (size_t)(b * 2 + 1) * NDIM * NDIM * NDIM;
    const float* __restrict__ x2 = img2 + (size_t)b * NDIM * NDIM * NDIM;

    float uW[5], vW[5], tW[5];
    #pragma unroll
    for (int i = 0; i < 5; ++i) { uW[i] = wfac[i]; vW[i] = wfac[5 + i]; tW[i] = wfac[10 + i]; }

    __shared__ float sWc[5][WR][SW];     // 10240 B; wave w owns cols [16w,16w+16)
    __shared__ float sRed[4];

    const int tid  = threadIdx.x;
    const int wvid = tid >> 6;           // wave id 0..3 -> 16-col stripe
    const int lane = tid & 63;
    // W-conv mapping (per wave): 8 rows x 8 col-groups of 2
    const int wrow = lane >> 3;          // 0..7
    const int wg   = lane & 7;           // 0..7
    const int c0b  = wvid * 16 + wg * 2; // block-local col of 2 outputs
    const int c0g  = cs + c0b;           // global col (even, 0..126)
    const int ghw  = h0 + wrow - 2;
    // H/D mapping (per wave): 4 rows x 16 single cols
    const int orow = lane >> 4;          // 0..3
    const int ocb  = wvid * 16 + (lane & 15);

    float ring[5][5];                    // [slot][field], static indices only
    float accS = 0.f;

#define PHASE(I, P) do {                                                       \
    const int i_ = (I);                                                        \
    const int d_ = d0 - 2 + i_;                                                \
    float2 A0 = make_float2(0.f, 0.f), A1 = A0, A2 = A0;                       \
    float2 B0 = A0, B1 = A0, B2 = A0;                                          \
    if (((unsigned)d_ < NDIM) && ((unsigned)ghw < NDIM)) {                     \
        const float* __restrict__ r1_ = x1 + ((size_t)d_ * NDIM + ghw) * NDIM; \
        const float* __restrict__ r2_ = x2 + ((size_t)d_ * NDIM + ghw) * NDIM; \
        if (c0g > 0)   { A0 = *(const float2*)(r1_ + c0g - 2);                 \
                         B0 = *(const float2*)(r2_ + c0g - 2); }               \
        A1 = *(const float2*)(r1_ + c0g);                                      \
        B1 = *(const float2*)(r2_ + c0g);                                      \
        if (c0g < 126) { A2 = *(const float2*)(r1_ + c0g + 2);                 \
                         B2 = *(const float2*)(r2_ + c0g + 2); }               \
    }                                                                          \
    float ra[6] = {A0.x,A0.y, A1.x,A1.y, A2.x,A2.y};                           \
    float rb[6] = {B0.x,B0.y, B1.x,B1.y, B2.x,B2.y};                           \
    float m1v[2], m2v[2], q11v[2], q22v[2], q12v[2];                           \
    _Pragma("unroll")                                                          \
    for (int k_ = 0; k_ < 2; ++k_) {                                           \
        float m1_=0.f, m2_=0.f, q11_=0.f, q22_=0.f, q12_=0.f;                  \
        _Pragma("unroll")                                                      \
        for (int c_ = 0; c_ < 5; ++c_) {                                       \
            const float a_ = ra[k_ + c_], b_ = rb[k_ + c_];                    \
            const float ta_ = tW[c_] * a_, tb_ = tW[c_] * b_;                  \
            m1_ += ta_; m2_ += tb_;                                            \
            q11_ += ta_ * a_; q22_ += tb_ * b_; q12_ += ta_ * b_;              \
        }                                                                      \
        m1v[k_]=m1_; m2v[k_]=m2_; q11v[k_]=q11_; q22v[k_]=q22_; q12v[k_]=q12_; \
    }                                                                          \
    /* fence: prior phase's intra-wave LDS reads ordered before these writes;  \
       HW processes a wave's DS ops in issue order. Also the scheduling fence  \
       that prevents cross-phase load-hoist spills (r4-r6). */                 \
    asm volatile("" ::: "memory");                                             \
    *(float2*)&sWc[0][wrow][c0b] = make_float2(m1v[0], m1v[1]);                \
    *(float2*)&sWc[1][wrow][c0b] = make_float2(m2v[0], m2v[1]);                \
    *(float2*)&sWc[2][wrow][c0b] = make_float2(q11v[0], q11v[1]);              \
    *(float2*)&sWc[3][wrow][c0b] = make_float2(q22v[0], q22v[1]);              \
    *(float2*)&sWc[4][wrow][c0b] = make_float2(q12v[0], q12v[1]);              \
    asm volatile("" ::: "memory");  /* writes ordered before the reads below */\
    _Pragma("unroll")                                                          \
    for (int f_ = 0; f_ < 5; ++f_) {                                           \
        float F_ = 0.f;                                                        \
        _Pragma("unroll")                                                      \
        for (int r_ = 0; r_ < 5; ++r_)                                         \
            F_ += vW[r_] * sWc[f_][orow + r_][ocb];                            \
        ring[(P)][f_] = F_;                                                    \
    }                                                                          \
    if (i_ >= 4) {                                                             \
        float F0 = 0.f, F1 = 0.f, F2 = 0.f, F3 = 0.f, F4 = 0.f;                \
        _Pragma("unroll")                                                      \
        for (int j_ = 0; j_ < 5; ++j_) {                                       \
            const int s_ = ((P) + 1 + j_) % 5;                                 \
            const float uw_ = uW[j_];                                          \
            F0 += uw_*ring[s_][0]; F1 += uw_*ring[s_][1];                      \
            F2 += uw_*ring[s_][2]; F3 += uw_*ring[s_][3];                      \
            F4 += uw_*ring[s_][4];                                             \
        }                                                                      \
        const float mu1 = F0, mu2 = F1;                                        \
        const float m11 = mu1*mu1, m22 = mu2*mu2, m12 = mu1*mu2;               \
        const float num = (2.f*m12 + 1e-4f) * (2.f*(F4 - m12) + 9e-4f);        \
        const float den = (m11 + m22 + 1e-4f) *                                \
                          ((F2 - m11) + (F3 - m22) + 9e-4f);                   \
        accS += __fdividef(num, den);                                          \
    }                                                                          \
} while (0)

    // 20 slices: d0-2 .. d0+17, 4 groups of 5 phases (known-good loop shape)
    for (int io = 0; io < 4; ++io) {
        const int ib = io * 5;
        PHASE(ib + 0, 0);
        PHASE(ib + 1, 1);
        PHASE(ib + 2, 2);
        PHASE(ib + 3, 3);
        PHASE(ib + 4, 4);
    }
#undef PHASE

    float acc = accS;
    #pragma unroll
    for (int off = 32; off > 0; off >>= 1)
        acc += __shfl_down(acc, off, 64);
    __syncthreads();                     // only cross-wave sync in the kernel
    if (lane == 0) sRed[wvid] = acc;
    __syncthreads();
    if (tid == 0) partials[bid] = sRed[0] + sRed[1] + sRed[2] + sRed[3];
}

__global__ void finalize_kernel(const float* __restrict__ partials, float* __restrict__ out) {
    const int tid = threadIdx.x;
    double s = 0.0;
    for (int i = tid; i < NBLK; i += 256) s += (double)partials[i];
    #pragma unroll
    for (int off = 32; off > 0; off >>= 1)
        s += __shfl_down(s, off, 64);
    __shared__ double sm[4];
    if ((tid & 63) == 0) sm[tid >> 6] = s;
    __syncthreads();
    if (tid == 0)
        out[0] = 1.0f - (float)((sm[0] + sm[1] + sm[2] + sm[3]) / (double)(4LL * 128 * 128 * 128));
}

extern "C" void kernel_launch(void* const* d_in, const int* in_sizes, int n_in,
                              void* d_out, int out_size, void* d_ws, size_t ws_size,
                              hipStream_t stream) {
    const float* img1 = (const float*)d_in[0];   // (4,2,128,128,128) fp32
    const float* img2 = (const float*)d_in[1];   // (4,1,128,128,128) fp32
    const float* win  = (const float*)d_in[2];   // (1,1,5,5,5) fp32
    float* out = (float*)d_out;
    float* ws  = (float*)d_ws;
    float* wfac     = ws;         // 16 floats
    float* partials = ws + 16;    // NBLK floats, fully rewritten every launch

    hipLaunchKernelGGL(factorize_window, dim3(1), dim3(64), 0, stream, win, wfac);
    hipLaunchKernelGGL(ssim_main, dim3(NBLK), dim3(256), 0, stream, img1, img2, wfac, partials);
    hipLaunchKernelGGL(finalize_kernel, dim3(1), dim3(256), 0, stream, partials, out);
}

// Round 8
// 162.643 us; speedup vs baseline: 3.8527x; 1.7119x over previous
//
#include <hip/hip_runtime.h>

// SSIM 3D, round 11 = round 8 (best verified: 66.6 µs main, 160.6 µs wall)
// + single-slice software prefetch + __launch_bounds__(256,2).
// Session allocator theory (explains ALL spills): arch-VGPR budget =
// 512/min_waves_per_EU/2 -> (256,8) pins 32 (r9), (256,4) pins 64 (r4/r5/r6/
// r10 all spill AT 64 rather than allocating 65+). r4's prefetch needed ~110
// regs under a 64 cap -> 600 MB scratch. (256,2) raises the cap to ~128 at
// ZERO occupancy cost: grid-capped 4 blocks/CU x 4 waves = 16 waves/CU, and
// VGPR<=128 still allows 4 waves/SIMD.
// Structure (verbatim from r8):
//  - Wave-private LDS: wave w owns all 8 W-rows x 32-col stripe -> producer ==
//    consumer wave -> ZERO barriers in main loop; asm memory fences at the two
//    former barrier sites (compiler ordering + anti-hoist scheduling fence).
//  - 4x5-phase loop, plain partials tail (known-good codegen shape).
// New: PHASE consumes prefetched ld[6] (float4 x 24 VGPR), runs W-conv, then
// issues LOADP(i+1) BEFORE the fences -> ~300-400 cyc HBM/L2 latency hides
// under LDS-write + H-conv + D-conv + next W-conv. Peak live ~115 regs.
// Tripwires: VGPR_Count ~96-124 expected (64 => pin theory wrong; >128 =>
// occupancy crash; either => revert to r8). WRITE_SIZE ~17 MB (spill detector;
// VGPR_Count alone lies about spills).
// Tile: W=128 (4 waves x 32 cols), TH=4 rows, DSUB=16 -> 1024 blocks.

#define NDIM 128
#define TH 4
#define WR (TH + 4)            // 8 W-conv rows
#define DSUB 16
#define NHT (NDIM / TH)        // 32
#define NDT (NDIM / DSUB)      // 8
#define NB 4
#define NBLK (NHT * NDT * NB)  // 1024

__global__ void factorize_window(const float* __restrict__ w, float* __restrict__ ws) {
    if (threadIdx.x == 0) {
        float w000 = w[0];
        #pragma unroll
        for (int i = 0; i < 5; ++i) ws[i]      = w[i * 25];
        #pragma unroll
        for (int j = 0; j < 5; ++j) ws[5 + j]  = w[j * 5] / w000;
        #pragma unroll
        for (int k = 0; k < 5; ++k) ws[10 + k] = w[k] / w000;
    }
}

__launch_bounds__(256, 2)
__global__ void ssim_main(const float* __restrict__ img1,
                          const float* __restrict__ img2,
                          const float* __restrict__ wfac,
                          float* __restrict__ partials) {
    const int bid = blockIdx.x;
    const int th = bid % NHT;
    const int td = (bid / NHT) % NDT;
    const int b  = bid / (NHT * NDT);

    const int h0 = th * TH, d0 = td * DSUB;
    const float* __restrict__ x1 = img1 + (size_t)(b * 2 + 1) * NDIM * NDIM * NDIM;
    const float* __restrict__ x2 = img2 + (size_t)b * NDIM * NDIM * NDIM;

    float uW[5], vW[5], tW[5];
    #pragma unroll
    for (int i = 0; i < 5; ++i) { uW[i] = wfac[i]; vW[i] = wfac[5 + i]; tW[i] = wfac[10 + i]; }

    __shared__ float sWc[5][WR][NDIM];   // 20 KB; wave w uses cols [32w,32w+32)
    __shared__ float sRed[4];

    const int tid  = threadIdx.x;
    const int wv   = tid >> 6;           // wave id 0..3 -> col stripe
    const int lane = tid & 63;
    const int sc   = wv * 32;            // stripe col base
    // W-conv mapping (per wave): 8 rows x 8 col-groups of 4
    const int wrow = lane >> 3;          // 0..7
    const int wg   = lane & 7;           // 0..7
    const int c0   = sc + wg * 4;        // global col of this lane's 4 outputs
    const int ghw  = h0 + wrow - 2;
    // H/D mapping (per wave): 4 rows x 16 col-pairs of 2
    const int orow = lane >> 4;          // 0..3
    const int oc   = sc + (lane & 15) * 2;

    float2 ring[5][5];                   // [slot][field], static indices only
    float2 accS = make_float2(0.f, 0.f);
    float4 ld[6];                        // prefetched slice: A0,A1,A2,B0,B1,B2

#define LOADP(IN) do {                                                         \
    const int ip_ = (IN);                                                      \
    const int dp_ = d0 - 2 + ip_;                                              \
    const float4 z_ = make_float4(0.f, 0.f, 0.f, 0.f);                         \
    ld[0]=z_; ld[1]=z_; ld[2]=z_; ld[3]=z_; ld[4]=z_; ld[5]=z_;                \
    if ((ip_ < DSUB + 4) && ((unsigned)dp_ < NDIM) && ((unsigned)ghw < NDIM)) {\
        const float* __restrict__ r1_ = x1 + ((size_t)dp_ * NDIM + ghw) * NDIM;\
        const float* __restrict__ r2_ = x2 + ((size_t)dp_ * NDIM + ghw) * NDIM;\
        if (c0 > 0)   { ld[0] = *(const float4*)(r1_ + c0 - 4);                \
                        ld[3] = *(const float4*)(r2_ + c0 - 4); }              \
        ld[1] = *(const float4*)(r1_ + c0);                                    \
        ld[4] = *(const float4*)(r2_ + c0);                                    \
        if (c0 < 124) { ld[2] = *(const float4*)(r1_ + c0 + 4);                \
                        ld[5] = *(const float4*)(r2_ + c0 + 4); }              \
    }                                                                          \
} while (0)

#define PHASE(I, P) do {                                                       \
    const int i_ = (I);                                                        \
    float ra[12] = {ld[0].x,ld[0].y,ld[0].z,ld[0].w,                           \
                    ld[1].x,ld[1].y,ld[1].z,ld[1].w,                           \
                    ld[2].x,ld[2].y,ld[2].z,ld[2].w};                          \
    float rb[12] = {ld[3].x,ld[3].y,ld[3].z,ld[3].w,                           \
                    ld[4].x,ld[4].y,ld[4].z,ld[4].w,                           \
                    ld[5].x,ld[5].y,ld[5].z,ld[5].w};                          \
    float m1v[4], m2v[4], q11v[4], q22v[4], q12v[4];                           \
    _Pragma("unroll")                                                          \
    for (int k_ = 0; k_ < 4; ++k_) {                                           \
        float m1_=0.f, m2_=0.f, q11_=0.f, q22_=0.f, q12_=0.f;                  \
        _Pragma("unroll")                                                      \
        for (int c_ = 0; c_ < 5; ++c_) {                                       \
            const float a_ = ra[k_ + c_ + 2], b_ = rb[k_ + c_ + 2];            \
            const float ta_ = tW[c_] * a_, tb_ = tW[c_] * b_;                  \
            m1_ += ta_; m2_ += tb_;                                            \
            q11_ += ta_ * a_; q22_ += tb_ * b_; q12_ += ta_ * b_;              \
        }                                                                      \
        m1v[k_]=m1_; m2v[k_]=m2_; q11v[k_]=q11_; q22v[k_]=q22_; q12v[k_]=q12_; \
    }                                                                          \
    LOADP(i_ + 1);  /* issue next-slice loads; latency hides under LDS write + \
                       H-conv + D-conv + next W-conv (~350+ inst window) */    \
    /* fence: prior phase's intra-wave LDS reads ordered before these writes;  \
       HW processes a wave's DS ops in issue order. Also the scheduling fence  \
       that prevents cross-phase hoisting (r4-r6 lesson). */                   \
    asm volatile("" ::: "memory");                                             \
    *(float4*)&sWc[0][wrow][c0] = make_float4(m1v[0],m1v[1],m1v[2],m1v[3]);    \
    *(float4*)&sWc[1][wrow][c0] = make_float4(m2v[0],m2v[1],m2v[2],m2v[3]);    \
    *(float4*)&sWc[2][wrow][c0] = make_float4(q11v[0],q11v[1],q11v[2],q11v[3]);\
    *(float4*)&sWc[3][wrow][c0] = make_float4(q22v[0],q22v[1],q22v[2],q22v[3]);\
    *(float4*)&sWc[4][wrow][c0] = make_float4(q12v[0],q12v[1],q12v[2],q12v[3]);\
    asm volatile("" ::: "memory");  /* writes ordered before the reads below */\
    _Pragma("unroll")                                                          \
    for (int f_ = 0; f_ < 5; ++f_) {                                           \
        float2 F_ = make_float2(0.f, 0.f);                                     \
        _Pragma("unroll")                                                      \
        for (int r_ = 0; r_ < 5; ++r_) {                                       \
            const float2 wv_ = *(const float2*)&sWc[f_][orow + r_][oc];        \
            F_.x += vW[r_] * wv_.x;                                            \
            F_.y += vW[r_] * wv_.y;                                            \
        }                                                                      \
        ring[(P)][f_] = F_;                                                    \
    }                                                                          \
    if (i_ >= 4) {                                                             \
        float2 F0 = make_float2(0,0), F1 = F0, F2 = F0, F3 = F0, F4 = F0;      \
        _Pragma("unroll")                                                      \
        for (int j_ = 0; j_ < 5; ++j_) {                                       \
            const int s_ = ((P) + 1 + j_) % 5;                                 \
            const float uw_ = uW[j_];                                          \
            F0.x += uw_*ring[s_][0].x; F0.y += uw_*ring[s_][0].y;              \
            F1.x += uw_*ring[s_][1].x; F1.y += uw_*ring[s_][1].y;              \
            F2.x += uw_*ring[s_][2].x; F2.y += uw_*ring[s_][2].y;              \
            F3.x += uw_*ring[s_][3].x; F3.y += uw_*ring[s_][3].y;              \
            F4.x += uw_*ring[s_][4].x; F4.y += uw_*ring[s_][4].y;              \
        }                                                                      \
        {                                                                      \
            const float mu1 = F0.x, mu2 = F1.x;                                \
            const float m11 = mu1*mu1, m22 = mu2*mu2, m12 = mu1*mu2;           \
            const float num = (2.f*m12 + 1e-4f) * (2.f*(F4.x - m12) + 9e-4f);  \
            const float den = (m11 + m22 + 1e-4f) *                            \
                              ((F2.x - m11) + (F3.x - m22) + 9e-4f);           \
            accS.x += __fdividef(num, den);                                    \
        }                                                                      \
        {                                                                      \
            const float mu1 = F0.y, mu2 = F1.y;                                \
            const float m11 = mu1*mu1, m22 = mu2*mu2, m12 = mu1*mu2;           \
            const float num = (2.f*m12 + 1e-4f) * (2.f*(F4.y - m12) + 9e-4f);  \
            const float den = (m11 + m22 + 1e-4f) *                            \
                              ((F2.y - m11) + (F3.y - m22) + 9e-4f);           \
            accS.y += __fdividef(num, den);                                    \
        }                                                                      \
    }                                                                          \
} while (0)

    // 20 slices: d0-2 .. d0+17, 4 groups of 5 phases (known-good loop shape)
    LOADP(0);
    for (int io = 0; io < 4; ++io) {
        const int ib = io * 5;
        PHASE(ib + 0, 0);
        PHASE(ib + 1, 1);
        PHASE(ib + 2, 2);
        PHASE(ib + 3, 3);
        PHASE(ib + 4, 4);
    }
#undef PHASE
#undef LOADP

    float acc = accS.x + accS.y;
    #pragma unroll
    for (int off = 32; off > 0; off >>= 1)
        acc += __shfl_down(acc, off, 64);
    __syncthreads();                     // only cross-wave sync in the kernel
    if (lane == 0) sRed[wv] = acc;
    __syncthreads();
    if (tid == 0) partials[bid] = sRed[0] + sRed[1] + sRed[2] + sRed[3];
}

__global__ void finalize_kernel(const float* __restrict__ partials, float* __restrict__ out) {
    const int tid = threadIdx.x;
    double s = 0.0;
    for (int i = tid; i < NBLK; i += 256) s += (double)partials[i];
    #pragma unroll
    for (int off = 32; off > 0; off >>= 1)
        s += __shfl_down(s, off, 64);
    __shared__ double sm[4];
    if ((tid & 63) == 0) sm[tid >> 6] = s;
    __syncthreads();
    if (tid == 0)
        out[0] = 1.0f - (float)((sm[0] + sm[1] + sm[2] + sm[3]) / (double)(4LL * 128 * 128 * 128));
}

extern "C" void kernel_launch(void* const* d_in, const int* in_sizes, int n_in,
                              void* d_out, int out_size, void* d_ws, size_t ws_size,
                              hipStream_t stream) {
    const float* img1 = (const float*)d_in[0];   // (4,2,128,128,128) fp32
    const float* img2 = (const float*)d_in[1];   // (4,1,128,128,128) fp32
    const float* win  = (const float*)d_in[2];   // (1,1,5,5,5) fp32
    float* out = (float*)d_out;
    float* ws  = (float*)d_ws;
    float* wfac     = ws;         // 16 floats
    float* partials = ws + 16;    // NBLK floats, fully rewritten every launch

    hipLaunchKernelGGL(factorize_window, dim3(1), dim3(64), 0, stream, win, wfac);
    hipLaunchKernelGGL(ssim_main, dim3(NBLK), dim3(256), 0, stream, img1, img2, wfac, partials);
    hipLaunchKernelGGL(finalize_kernel, dim3(1), dim3(256), 0, stream, partials, out);
}